// Round 1
// baseline (926.166 us; speedup 1.0000x reference)
//
#include <hip/hip_runtime.h>

// SSIM 3D loss, window 7^3, VALID. Shapes fixed by the reference:
// pred/targ: (4,1,32,320,320) f32; data_range: (4,) f32; out: scalar f32.

#define WIN 7
#define NPIX 343

constexpr int B = 4, T = 32, H = 320, W = 320;
constexpr int TO = T - (WIN - 1);   // 26
constexpr int HO = H - (WIN - 1);   // 314
constexpr int WO = W - (WIN - 1);   // 314
constexpr long long NOUT = (long long)B * TO * HO * WO;  // 10,253,984

__global__ __launch_bounds__(256) void ssim3d_kernel(
    const float* __restrict__ pred,
    const float* __restrict__ targ,
    const float* __restrict__ drange,
    double* __restrict__ acc)
{
    long long idx = (long long)blockIdx.x * blockDim.x + threadIdx.x;
    float val = 0.0f;
    if (idx < NOUT) {
        int w = (int)(idx % WO);
        long long r = idx / WO;
        int h = (int)(r % HO);
        r /= HO;
        int t = (int)(r % TO);
        int b = (int)(r / TO);

        const float* pb = pred + (long long)b * T * H * W;
        const float* tb = targ + (long long)b * T * H * W;

        float sx = 0.f, sy = 0.f, sxx = 0.f, syy = 0.f, sxy = 0.f;
        for (int dz = 0; dz < WIN; ++dz) {
            const float* pz = pb + (long long)(t + dz) * H * W;
            const float* tz = tb + (long long)(t + dz) * H * W;
            for (int dy = 0; dy < WIN; ++dy) {
                const float* py = pz + (h + dy) * W + w;
                const float* ty = tz + (h + dy) * W + w;
#pragma unroll
                for (int dw = 0; dw < WIN; ++dw) {
                    float p = py[dw];
                    float q = ty[dw];
                    sx += p;
                    sy += q;
                    sxx = fmaf(p, p, sxx);
                    syy = fmaf(q, q, syy);
                    sxy = fmaf(p, q, sxy);
                }
            }
        }
        const float inv = 1.0f / (float)NPIX;
        float ux  = sx  * inv;
        float uy  = sy  * inv;
        float uxx = sxx * inv;
        float uyy = syy * inv;
        float uxy = sxy * inv;
        const float covn = (float)NPIX / (float)(NPIX - 1);
        float vx  = covn * (uxx - ux * ux);
        float vy  = covn * (uyy - uy * uy);
        float vxy = covn * (uxy - ux * uy);
        float dr = drange[b];
        float C1 = (0.01f * dr) * (0.01f * dr);
        float C2 = (0.03f * dr) * (0.03f * dr);
        float A1 = 2.0f * ux * uy + C1;
        float A2 = 2.0f * vxy + C2;
        float B1 = ux * ux + uy * uy + C1;
        float B2 = vx + vy + C2;
        float S = (A1 * A2) / (B1 * B2);
        val = 1.0f - S;
    }

    // Block reduction: wave64 shfl, then LDS across 4 waves.
    for (int off = 32; off > 0; off >>= 1)
        val += __shfl_down(val, off, 64);
    __shared__ float wsum[4];
    int lane = threadIdx.x & 63;
    int wid  = threadIdx.x >> 6;
    if (lane == 0) wsum[wid] = val;
    __syncthreads();
    if (threadIdx.x == 0) {
        float s = wsum[0] + wsum[1] + wsum[2] + wsum[3];
        atomicAdd(acc, (double)s);
    }
}

__global__ void ssim3d_finalize(const double* __restrict__ acc,
                                float* __restrict__ out)
{
    out[0] = (float)(acc[0] / (double)NOUT);
}

extern "C" void kernel_launch(void* const* d_in, const int* in_sizes, int n_in,
                              void* d_out, int out_size, void* d_ws, size_t ws_size,
                              hipStream_t stream)
{
    const float* pred   = (const float*)d_in[0];
    const float* targ   = (const float*)d_in[1];
    const float* drange = (const float*)d_in[2];
    float* out = (float*)d_out;
    double* acc = (double*)d_ws;

    hipMemsetAsync(acc, 0, sizeof(double), stream);

    long long nblocks = (NOUT + 255) / 256;
    ssim3d_kernel<<<(int)nblocks, 256, 0, stream>>>(pred, targ, drange, acc);
    ssim3d_finalize<<<1, 1, 0, stream>>>(acc, out);
}

// Round 2
// 144.995 us; speedup vs baseline: 6.3876x; 6.3876x over previous
//
#include <hip/hip_runtime.h>

// Fused 3D SSIM, window 7^3, VALID. pred/targ: (4,1,32,320,320) f32.
// Block = 16x16 output tile in (h,w); serial walk over t with a 7-deep
// register ring buffer of 2D box sums (5 fields). Separable sums via LDS.

#define WIN 7
#define NPIX 343

constexpr int B = 4, T = 32, H = 320, W = 320;
constexpr int TO = T - (WIN - 1);   // 26
constexpr int HO = H - (WIN - 1);   // 314
constexpr int WO = W - (WIN - 1);   // 314
constexpr long long NOUT = (long long)B * TO * HO * WO;

constexpr int TILE  = 16;                    // output tile side
constexpr int ITILE = TILE + WIN - 1;        // 22 input tile side
constexpr int LDW   = 24;                    // padded LDS row stride
constexpr int NTIL  = (HO + TILE - 1) / TILE; // 20 tiles per axis

__global__ __launch_bounds__(256) void ssim3d_fused(
    const float* __restrict__ pred,
    const float* __restrict__ targ,
    const float* __restrict__ drange,
    double* __restrict__ acc)
{
    __shared__ float sp[ITILE][LDW];
    __shared__ float sq[ITILE][LDW];
    __shared__ float cs[5][TILE][LDW];
    __shared__ float wsum[4];

    const int bx  = blockIdx.x;
    const int b   = bx / (NTIL * NTIL);
    const int rem = bx % (NTIL * NTIL);
    const int h0  = (rem / NTIL) * TILE;
    const int w0  = (rem % NTIL) * TILE;

    const int tid = threadIdx.x;
    const int oh  = tid / TILE;   // 0..15 output row in tile
    const int ow  = tid % TILE;   // 0..15 output col in tile

    const float* pb = pred + (long long)b * T * H * W;
    const float* qb = targ + (long long)b * T * H * W;

    // 7-deep ring of 2D box sums, 5 fields, in registers (indices static
    // because the j-loop below is fully unrolled).
    float rx[7], ry[7], rxx[7], ryy[7], rxy[7];
#pragma unroll
    for (int i = 0; i < 7; ++i) { rx[i]=ry[i]=rxx[i]=ryy[i]=rxy[i]=0.f; }
    float tx_=0.f, ty_=0.f, txx=0.f, tyy=0.f, txy=0.f;

    const float dr = drange[b];
    const float C1 = (0.01f * dr) * (0.01f * dr);
    const float C2 = (0.03f * dr) * (0.03f * dr);
    const bool valid_hw = (h0 + oh < HO) && (w0 + ow < WO);

    float loss = 0.f;

    for (int tb = 0; tb < T; tb += 7) {
#pragma unroll
        for (int j = 0; j < 7; ++j) {
            const int t = tb + j;
            if (t < T) {
                // ---- stage input slice tile into LDS (clamped at edges) ----
                const float* ps = pb + (long long)t * H * W;
                const float* qs = qb + (long long)t * H * W;
                for (int i = tid; i < ITILE * ITILE; i += 256) {
                    int r = i / ITILE, c = i % ITILE;
                    int gr = h0 + r; gr = gr < H ? gr : H - 1;
                    int gc = w0 + c; gc = gc < W ? gc : W - 1;
                    long long off = (long long)gr * W + gc;
                    sp[r][c] = ps[off];
                    sq[r][c] = qs[off];
                }
                __syncthreads();

                // ---- column sums (7 tall) for 5 fields -> cs ----
                for (int i2 = tid; i2 < TILE * ITILE; i2 += 256) {
                    int hh = i2 / ITILE, wc = i2 % ITILE;
                    float ax=0.f, ay=0.f, axx=0.f, ayy=0.f, axy=0.f;
#pragma unroll
                    for (int dy = 0; dy < WIN; ++dy) {
                        float p = sp[hh + dy][wc];
                        float q = sq[hh + dy][wc];
                        ax += p; ay += q;
                        axx = fmaf(p, p, axx);
                        ayy = fmaf(q, q, ayy);
                        axy = fmaf(p, q, axy);
                    }
                    cs[0][hh][wc] = ax;
                    cs[1][hh][wc] = ay;
                    cs[2][hh][wc] = axx;
                    cs[3][hh][wc] = ayy;
                    cs[4][hh][wc] = axy;
                }
                __syncthreads();

                // ---- row sums (7 wide) -> this slice's 2D box sums ----
                float sx=0.f, sy=0.f, sxx=0.f, syy=0.f, sxy=0.f;
#pragma unroll
                for (int dx = 0; dx < WIN; ++dx) {
                    sx  += cs[0][oh][ow + dx];
                    sy  += cs[1][oh][ow + dx];
                    sxx += cs[2][oh][ow + dx];
                    syy += cs[3][oh][ow + dx];
                    sxy += cs[4][oh][ow + dx];
                }

                // ---- temporal sliding window: slot = t % 7 == j ----
                tx_ += sx  - rx[j];   rx[j]  = sx;
                ty_ += sy  - ry[j];   ry[j]  = sy;
                txx += sxx - rxx[j];  rxx[j] = sxx;
                tyy += syy - ryy[j];  ryy[j] = syy;
                txy += sxy - rxy[j];  rxy[j] = sxy;

                // ---- emit output for t_out = t - 6 ----
                if (t >= WIN - 1 && valid_hw) {
                    const float inv  = 1.0f / (float)NPIX;
                    const float covn = (float)NPIX / (float)(NPIX - 1);
                    float ux  = tx_ * inv;
                    float uy  = ty_ * inv;
                    float uxx = txx * inv;
                    float uyy = tyy * inv;
                    float uxy = txy * inv;
                    float vx  = covn * (uxx - ux * ux);
                    float vy  = covn * (uyy - uy * uy);
                    float vxy = covn * (uxy - ux * uy);
                    float A1 = 2.0f * ux * uy + C1;
                    float A2 = 2.0f * vxy + C2;
                    float B1 = ux * ux + uy * uy + C1;
                    float B2 = vx + vy + C2;
                    float S  = (A1 * A2) / (B1 * B2);
                    loss += 1.0f - S;
                }
            }
        }
    }

    // ---- block reduction -> global atomic ----
    for (int off = 32; off > 0; off >>= 1)
        loss += __shfl_down(loss, off, 64);
    const int lane = tid & 63;
    const int wid  = tid >> 6;
    if (lane == 0) wsum[wid] = loss;
    __syncthreads();
    if (tid == 0) {
        float s = wsum[0] + wsum[1] + wsum[2] + wsum[3];
        atomicAdd(acc, (double)s);
    }
}

__global__ void ssim3d_finalize(const double* __restrict__ acc,
                                float* __restrict__ out)
{
    out[0] = (float)(acc[0] / (double)NOUT);
}

extern "C" void kernel_launch(void* const* d_in, const int* in_sizes, int n_in,
                              void* d_out, int out_size, void* d_ws, size_t ws_size,
                              hipStream_t stream)
{
    const float* pred   = (const float*)d_in[0];
    const float* targ   = (const float*)d_in[1];
    const float* drange = (const float*)d_in[2];
    float* out  = (float*)d_out;
    double* acc = (double*)d_ws;

    hipMemsetAsync(acc, 0, sizeof(double), stream);

    const int nblocks = B * NTIL * NTIL;  // 1600
    ssim3d_fused<<<nblocks, 256, 0, stream>>>(pred, targ, drange, acc);
    ssim3d_finalize<<<1, 1, 0, stream>>>(acc, out);
}

// Round 3
// 114.990 us; speedup vs baseline: 8.0543x; 1.2609x over previous
//
#include <hip/hip_runtime.h>

// Fused 3D SSIM, window 7^3, VALID. pred/targ: (4,1,32,320,320) f32.
// Block = 16x16 output tile in (h,w); serial walk over t with a 7-deep
// register ring of 2D box sums (5 fields). Per slice:
//   stage (float4, prefetch-pipelined) -> column sums over h (float2 pairs,
//   also pairwise col2 sums) -> row gather = 4*col2 + 1 edge col.
// LDS strides chosen for <=2-way (free) bank aliasing on the hot reads.

#define WIN 7
#define NPIX 343

constexpr int B = 4, T = 32, H = 320, W = 320;
constexpr int TO = T - (WIN - 1);   // 26
constexpr int HO = H - (WIN - 1);   // 314
constexpr int WO = W - (WIN - 1);   // 314
constexpr long long NOUT = (long long)B * TO * HO * WO;

constexpr int TILE  = 16;            // output tile side
constexpr int ITILE = 22;            // input tile side
constexpr int SPW   = 24;            // sp/sq row stride (floats), float4-safe
constexpr int CW    = 24;            // col row stride: 24*oh mod 32 = {0,24,16,8}
constexpr int C2W   = 12;            // col2 row stride: 12*oh mod 32 = {0,12,24,4}
constexpr int NTIL  = (HO + TILE - 1) / TILE;  // 20

__global__ __launch_bounds__(256) void ssim3d_fused(
    const float* __restrict__ pred,
    const float* __restrict__ targ,
    const float* __restrict__ drange,
    double* __restrict__ acc)
{
    __shared__ float sp[ITILE][SPW];
    __shared__ float sq[ITILE][SPW];
    __shared__ float col [5][TILE][CW];
    __shared__ float col2[5][TILE][C2W];
    __shared__ float wsum[4];

    const int bx  = blockIdx.x;
    const int b   = bx / (NTIL * NTIL);
    const int rem = bx % (NTIL * NTIL);
    const int h0  = (rem / NTIL) * TILE;
    const int w0  = (rem % NTIL) * TILE;

    const int tid = threadIdx.x;
    const int oh  = tid >> 4;          // 0..15
    const int ow  = tid & 15;          // 0..15

    const float* pb = pred + (long long)b * T * H * W;
    const float* qb = targ + (long long)b * T * H * W;

    // staging mapping: 132 items = 22 rows x 6 float4-columns, both fields
    const int sr  = tid / 6;           // 0..21 (tid<132)
    const int sc4 = tid - 6 * sr;      // 0..5
    const int gr  = min(h0 + sr, H - 1);
    const int gcb = min(w0 + 4 * sc4, W - 4);   // clamped float4 base (aligned)
    const bool stager = (tid < 132);

    // column-pair mapping: 176 items = 16 rows x 11 pairs
    const int ch = oh;                 // 0..15
    const int cj = ow;                 // pair index, active if < 11
    const bool colw = (cj < 11);
    const int j2 = cj * 2;

    // row-gather constants
    const int j0   = ow >> 1;
    const int edge = (ow & 1) ? (ow - 1) : (ow + 7);
    const bool valid_hw = (h0 + oh < HO) && (w0 + ow < WO);

    const float dr = drange[b];
    const float C1 = (0.01f * dr) * (0.01f * dr);
    const float C2 = (0.03f * dr) * (0.03f * dr);

    float rx[7], ry[7], rxx[7], ryy[7], rxy[7];
#pragma unroll
    for (int i = 0; i < 7; ++i) { rx[i]=ry[i]=rxx[i]=ryy[i]=rxy[i]=0.f; }
    float tx_=0.f, ty_=0.f, txx=0.f, tyy=0.f, txy=0.f;
    float loss = 0.f;

    float4 pr, qr;
    auto prefetch = [&](int t) {
        if (stager) {
            const float* ps = pb + ((long long)t * H + gr) * W + gcb;
            const float* qs = qb + ((long long)t * H + gr) * W + gcb;
            pr = *reinterpret_cast<const float4*>(ps);
            qr = *reinterpret_cast<const float4*>(qs);
        }
    };

    prefetch(0);

    for (int tb = 0; tb < T; tb += 7) {
#pragma unroll
        for (int j = 0; j < 7; ++j) {
            const int t = tb + j;
            if (t < T) {
                // ---- commit prefetched slice into LDS ----
                if (stager) {
                    *reinterpret_cast<float4*>(&sp[sr][4 * sc4]) = pr;
                    *reinterpret_cast<float4*>(&sq[sr][4 * sc4]) = qr;
                }
                __syncthreads();

                // ---- issue next slice's global loads (latency hidden) ----
                if (t + 1 < T) prefetch(t + 1);

                // ---- column sums over h, pairs of columns via float2 ----
                if (colw) {
                    float ax0=0,ax1=0, ay0=0,ay1=0;
                    float axx0=0,axx1=0, ayy0=0,ayy1=0, axy0=0,axy1=0;
#pragma unroll
                    for (int dy = 0; dy < WIN; ++dy) {
                        float2 p = *reinterpret_cast<const float2*>(&sp[ch + dy][j2]);
                        float2 q = *reinterpret_cast<const float2*>(&sq[ch + dy][j2]);
                        ax0 += p.x; ax1 += p.y;
                        ay0 += q.x; ay1 += q.y;
                        axx0 = fmaf(p.x, p.x, axx0); axx1 = fmaf(p.y, p.y, axx1);
                        ayy0 = fmaf(q.x, q.x, ayy0); ayy1 = fmaf(q.y, q.y, ayy1);
                        axy0 = fmaf(p.x, q.x, axy0); axy1 = fmaf(p.y, q.y, axy1);
                    }
                    *reinterpret_cast<float2*>(&col[0][ch][j2]) = make_float2(ax0, ax1);
                    *reinterpret_cast<float2*>(&col[1][ch][j2]) = make_float2(ay0, ay1);
                    *reinterpret_cast<float2*>(&col[2][ch][j2]) = make_float2(axx0, axx1);
                    *reinterpret_cast<float2*>(&col[3][ch][j2]) = make_float2(ayy0, ayy1);
                    *reinterpret_cast<float2*>(&col[4][ch][j2]) = make_float2(axy0, axy1);
                    col2[0][ch][cj] = ax0 + ax1;
                    col2[1][ch][cj] = ay0 + ay1;
                    col2[2][ch][cj] = axx0 + axx1;
                    col2[3][ch][cj] = ayy0 + ayy1;
                    col2[4][ch][cj] = axy0 + axy1;
                }
                __syncthreads();

                // ---- row gather: 7-wide sum = 4*col2 (8 cols) - edge col ----
                float sx  = col2[0][oh][j0] + col2[0][oh][j0+1] + col2[0][oh][j0+2] + col2[0][oh][j0+3] - col[0][oh][edge];
                float sy  = col2[1][oh][j0] + col2[1][oh][j0+1] + col2[1][oh][j0+2] + col2[1][oh][j0+3] - col[1][oh][edge];
                float sxx = col2[2][oh][j0] + col2[2][oh][j0+1] + col2[2][oh][j0+2] + col2[2][oh][j0+3] - col[2][oh][edge];
                float syy = col2[3][oh][j0] + col2[3][oh][j0+1] + col2[3][oh][j0+2] + col2[3][oh][j0+3] - col[3][oh][edge];
                float sxy = col2[4][oh][j0] + col2[4][oh][j0+1] + col2[4][oh][j0+2] + col2[4][oh][j0+3] - col[4][oh][edge];

                // ---- temporal sliding window: slot = t % 7 == j ----
                tx_ += sx  - rx[j];   rx[j]  = sx;
                ty_ += sy  - ry[j];   ry[j]  = sy;
                txx += sxx - rxx[j];  rxx[j] = sxx;
                tyy += syy - ryy[j];  ryy[j] = syy;
                txy += sxy - rxy[j];  rxy[j] = sxy;

                // ---- emit output for t_out = t - 6 ----
                if (t >= WIN - 1 && valid_hw) {
                    const float inv  = 1.0f / (float)NPIX;
                    const float covn = (float)NPIX / (float)(NPIX - 1);
                    float ux  = tx_ * inv;
                    float uy  = ty_ * inv;
                    float uxx = txx * inv;
                    float uyy = tyy * inv;
                    float uxy = txy * inv;
                    float vx  = covn * (uxx - ux * ux);
                    float vy  = covn * (uyy - uy * uy);
                    float vxy = covn * (uxy - ux * uy);
                    float A1 = 2.0f * ux * uy + C1;
                    float A2 = 2.0f * vxy + C2;
                    float B1 = ux * ux + uy * uy + C1;
                    float B2 = vx + vy + C2;
                    float S  = (A1 * A2) / (B1 * B2);
                    loss += 1.0f - S;
                }
            }
        }
    }

    // ---- block reduction -> global atomic ----
    for (int off = 32; off > 0; off >>= 1)
        loss += __shfl_down(loss, off, 64);
    const int lane = tid & 63;
    const int wid  = tid >> 6;
    if (lane == 0) wsum[wid] = loss;
    __syncthreads();
    if (tid == 0) {
        float s = wsum[0] + wsum[1] + wsum[2] + wsum[3];
        atomicAdd(acc, (double)s);
    }
}

__global__ void ssim3d_finalize(const double* __restrict__ acc,
                                float* __restrict__ out)
{
    out[0] = (float)(acc[0] / (double)NOUT);
}

extern "C" void kernel_launch(void* const* d_in, const int* in_sizes, int n_in,
                              void* d_out, int out_size, void* d_ws, size_t ws_size,
                              hipStream_t stream)
{
    const float* pred   = (const float*)d_in[0];
    const float* targ   = (const float*)d_in[1];
    const float* drange = (const float*)d_in[2];
    float* out  = (float*)d_out;
    double* acc = (double*)d_ws;

    hipMemsetAsync(acc, 0, sizeof(double), stream);

    const int nblocks = B * NTIL * NTIL;  // 1600
    ssim3d_fused<<<nblocks, 256, 0, stream>>>(pred, targ, drange, acc);
    ssim3d_finalize<<<1, 1, 0, stream>>>(acc, out);
}

// Round 4
// 96.059 us; speedup vs baseline: 9.6417x; 1.1971x over previous
//
#include <hip/hip_runtime.h>

// Fused 3D SSIM, window 7^3, VALID. pred/targ: (4,1,32,320,320) f32.
// Block = 16x16 output tile in (h,w) x 13 t-outputs (t-range split in 2).
// Single barrier per slice: double-buffered sp/sq and col/col2.
// Per slice: commit prefetched slice s+1 | column sums of slice s | prefetch
// s+2  -> barrier -> row gather (3 pairs + 1 single) + temporal ring update.

#define WIN 7
#define NPIX 343

constexpr int B = 4, T = 32, H = 320, W = 320;
constexpr int TO = T - (WIN - 1);   // 26
constexpr int HO = H - (WIN - 1);   // 314
constexpr int WO = W - (WIN - 1);   // 314
constexpr long long NOUT = (long long)B * TO * HO * WO;

constexpr int TILE  = 16;            // output tile side
constexpr int ITILE = 22;            // input tile side
constexpr int SPW   = 24;            // sp/sq row stride
constexpr int CW    = 24;            // col row stride
constexpr int C2W   = 12;            // col2 row stride
constexpr int NTIL  = (HO + TILE - 1) / TILE;  // 20
constexpr int OT_PER = 13;           // t-outputs per half-block
constexpr int NS     = OT_PER + WIN - 1;  // 19 slices read per half

__global__ __launch_bounds__(256) void ssim3d_fused(
    const float* __restrict__ pred,
    const float* __restrict__ targ,
    const float* __restrict__ drange,
    double* __restrict__ acc)
{
    __shared__ float sp[2][ITILE][SPW];
    __shared__ float sq[2][ITILE][SPW];
    __shared__ float col [2][5][TILE][CW];
    __shared__ float col2[2][5][TILE][C2W];
    __shared__ float wsum[4];

    const int bx   = blockIdx.x;
    const int b    = bx / (2 * NTIL * NTIL);
    const int rem  = bx % (2 * NTIL * NTIL);
    const int half = rem / (NTIL * NTIL);
    const int r2   = rem % (NTIL * NTIL);
    const int h0   = (r2 / NTIL) * TILE;
    const int w0   = (r2 % NTIL) * TILE;
    const int t0   = half * OT_PER;          // first slice of this half

    const int tid = threadIdx.x;
    const int oh  = tid >> 4;          // 0..15
    const int ow  = tid & 15;          // 0..15

    const float* pb = pred + (long long)b * T * H * W;
    const float* qb = targ + (long long)b * T * H * W;

    // staging: 242 threads, each one float2 per field: row, pair-col
    const int sr  = tid / 11;                    // 0..21 when tid<242
    const int sc  = tid - 11 * sr;               // 0..10
    const int gr  = min(h0 + sr, H - 1);
    const int gc  = min(w0 + 2 * sc, W - 2);
    const bool stager = (tid < 242);
    const long long gbase = (long long)gr * W + gc;

    // column-pair phase mapping (same (oh, ow<11) shape)
    const bool colw = (ow < 11);
    const int  j2   = ow * 2;

    // row gather: 3 col2 pairs + 1 single col
    const int pbase  = (ow + 1) >> 1;
    const int single = (ow & 1) ? ow : ow + 6;
    const bool valid_hw = (h0 + oh < HO) && (w0 + ow < WO);

    const float dr = drange[b];
    const float C1 = (0.01f * dr) * (0.01f * dr);
    const float C2 = (0.03f * dr) * (0.03f * dr);

    float rx[7], ry[7], rxx[7], ryy[7], rxy[7];
#pragma unroll
    for (int i = 0; i < 7; ++i) { rx[i]=ry[i]=rxx[i]=ryy[i]=rxy[i]=0.f; }
    float tx_=0.f, ty_=0.f, txx=0.f, tyy=0.f, txy=0.f;
    float loss = 0.f;

    float2 pr, qr;
    auto prefetch = [&](int s) {
        if (stager) {
            const long long off = (long long)(t0 + s) * H * W + gbase;
            pr = *reinterpret_cast<const float2*>(pb + off);
            qr = *reinterpret_cast<const float2*>(qb + off);
        }
    };
    auto commit = [&](int buf) {
        if (stager) {
            *reinterpret_cast<float2*>(&sp[buf][sr][2 * sc]) = pr;
            *reinterpret_cast<float2*>(&sq[buf][sr][2 * sc]) = qr;
        }
    };

    // prologue
    prefetch(0);
    commit(0);
    prefetch(1);
    __syncthreads();

    for (int a = 0; a < 21; a += 7) {
#pragma unroll
        for (int j = 0; j < 7; ++j) {
            const int s = a + j;
            if (s < NS) {
                const int bs = s & 1, bn = bs ^ 1;

                // commit slice s+1 into the other buffer
                if (s + 1 < NS) commit(bn);

                // column sums over h for slice s (pairs via float2)
                if (colw) {
                    float ax0=0,ax1=0, ay0=0,ay1=0;
                    float axx0=0,axx1=0, ayy0=0,ayy1=0, axy0=0,axy1=0;
#pragma unroll
                    for (int dy = 0; dy < WIN; ++dy) {
                        float2 p = *reinterpret_cast<const float2*>(&sp[bs][oh + dy][j2]);
                        float2 q = *reinterpret_cast<const float2*>(&sq[bs][oh + dy][j2]);
                        ax0 += p.x; ax1 += p.y;
                        ay0 += q.x; ay1 += q.y;
                        axx0 = fmaf(p.x, p.x, axx0); axx1 = fmaf(p.y, p.y, axx1);
                        ayy0 = fmaf(q.x, q.x, ayy0); ayy1 = fmaf(q.y, q.y, ayy1);
                        axy0 = fmaf(p.x, q.x, axy0); axy1 = fmaf(p.y, q.y, axy1);
                    }
                    *reinterpret_cast<float2*>(&col[bs][0][oh][j2]) = make_float2(ax0, ax1);
                    *reinterpret_cast<float2*>(&col[bs][1][oh][j2]) = make_float2(ay0, ay1);
                    *reinterpret_cast<float2*>(&col[bs][2][oh][j2]) = make_float2(axx0, axx1);
                    *reinterpret_cast<float2*>(&col[bs][3][oh][j2]) = make_float2(ayy0, ayy1);
                    *reinterpret_cast<float2*>(&col[bs][4][oh][j2]) = make_float2(axy0, axy1);
                    col2[bs][0][oh][ow] = ax0 + ax1;
                    col2[bs][1][oh][ow] = ay0 + ay1;
                    col2[bs][2][oh][ow] = axx0 + axx1;
                    col2[bs][3][oh][ow] = ayy0 + ayy1;
                    col2[bs][4][oh][ow] = axy0 + axy1;
                }

                // prefetch slice s+2 (hidden under colsum + barrier)
                if (s + 2 < NS) prefetch(s + 2);

                __syncthreads();   // col[bs] ready; sp[bn] committed

                // row gather: 7-wide = 3 pairs + 1 single
                float sx  = col2[bs][0][oh][pbase] + col2[bs][0][oh][pbase+1] + col2[bs][0][oh][pbase+2] + col[bs][0][oh][single];
                float sy  = col2[bs][1][oh][pbase] + col2[bs][1][oh][pbase+1] + col2[bs][1][oh][pbase+2] + col[bs][1][oh][single];
                float sxx = col2[bs][2][oh][pbase] + col2[bs][2][oh][pbase+1] + col2[bs][2][oh][pbase+2] + col[bs][2][oh][single];
                float syy = col2[bs][3][oh][pbase] + col2[bs][3][oh][pbase+1] + col2[bs][3][oh][pbase+2] + col[bs][3][oh][single];
                float sxy = col2[bs][4][oh][pbase] + col2[bs][4][oh][pbase+1] + col2[bs][4][oh][pbase+2] + col[bs][4][oh][single];

                // temporal sliding window, slot j = s % 7
                tx_ += sx  - rx[j];   rx[j]  = sx;
                ty_ += sy  - ry[j];   ry[j]  = sy;
                txx += sxx - rxx[j];  rxx[j] = sxx;
                tyy += syy - ryy[j];  ryy[j] = syy;
                txy += sxy - rxy[j];  rxy[j] = sxy;

                // emit output for t_out = t0 + s - 6
                if (s >= WIN - 1 && valid_hw) {
                    const float inv  = 1.0f / (float)NPIX;
                    const float covn = (float)NPIX / (float)(NPIX - 1);
                    float ux  = tx_ * inv;
                    float uy  = ty_ * inv;
                    float uxx = txx * inv;
                    float uyy = tyy * inv;
                    float uxy = txy * inv;
                    float vx  = covn * (uxx - ux * ux);
                    float vy  = covn * (uyy - uy * uy);
                    float vxy = covn * (uxy - ux * uy);
                    float A1 = 2.0f * ux * uy + C1;
                    float A2 = 2.0f * vxy + C2;
                    float B1 = ux * ux + uy * uy + C1;
                    float B2 = vx + vy + C2;
                    float S  = (A1 * A2) / (B1 * B2);
                    loss += 1.0f - S;
                }
            }
        }
    }

    // block reduction -> global atomic
    for (int off = 32; off > 0; off >>= 1)
        loss += __shfl_down(loss, off, 64);
    const int lane = tid & 63;
    const int wid  = tid >> 6;
    if (lane == 0) wsum[wid] = loss;
    __syncthreads();
    if (tid == 0) {
        float s = wsum[0] + wsum[1] + wsum[2] + wsum[3];
        atomicAdd(acc, (double)s);
    }
}

__global__ void ssim3d_finalize(const double* __restrict__ acc,
                                float* __restrict__ out)
{
    out[0] = (float)(acc[0] / (double)NOUT);
}

extern "C" void kernel_launch(void* const* d_in, const int* in_sizes, int n_in,
                              void* d_out, int out_size, void* d_ws, size_t ws_size,
                              hipStream_t stream)
{
    const float* pred   = (const float*)d_in[0];
    const float* targ   = (const float*)d_in[1];
    const float* drange = (const float*)d_in[2];
    float* out  = (float*)d_out;
    double* acc = (double*)d_ws;

    hipMemsetAsync(acc, 0, sizeof(double), stream);

    const int nblocks = B * 2 * NTIL * NTIL;  // 3200
    ssim3d_fused<<<nblocks, 256, 0, stream>>>(pred, targ, drange, acc);
    ssim3d_finalize<<<1, 1, 0, stream>>>(acc, out);
}

// Round 5
// 85.396 us; speedup vs baseline: 10.8456x; 1.1249x over previous
//
#include <hip/hip_runtime.h>

// Fused 3D SSIM, window 7^3, VALID. pred/targ: (4,1,32,320,320) f32.
// Tile = 16h x 32w outputs, 2 adjacent w-outputs per thread; t split in 2
// halves (13 outputs each, 19 slices). One barrier per slice, double-buffered
// sp/sq + col/col2. 4 tracked fields (SSIM needs only vx+vy and vxy):
//   f0=sum p, f1=sum q, f2=sum p^2+q^2, f3=sum p*q.
// Per slice: commit staged slice s+1 | row-paired column sums of slice s |
// prefetch s+2 -> barrier -> 8-wide rowgather (4 col2 + 2 singles for 2
// outputs) + temporal register ring.

#define WIN 7
#define NPIX 343

constexpr int B = 4, T = 32, H = 320, W = 320;
constexpr int TO = T - 6, HO = H - 6, WO = W - 6;   // 26, 314, 314
constexpr long long NOUT = (long long)B * TO * HO * WO;

constexpr int TH = 16, TW = 32;      // output tile
constexpr int IH = 22;               // input tile rows (+6 halo)
constexpr int SPW = 44;              // sp/sq row stride (f4-aligned, bank-spread)
constexpr int CW  = 41;              // col row stride (odd: rows alternate parity)
constexpr int C2W = 24;              // col2 row stride (each bank exactly 2-way)
constexpr int NTH = 20, NTW = 10;    // ceil(314/16), ceil(314/32)
constexpr int OT_PER = 13, NS = OT_PER + 6;  // 19 slices per half

__global__ __launch_bounds__(256) void ssim3d_fused(
    const float* __restrict__ pred,
    const float* __restrict__ targ,
    const float* __restrict__ drange,
    double* __restrict__ acc)
{
    __shared__ float sp[2][IH][SPW];
    __shared__ float sq[2][IH][SPW];
    __shared__ float col [2][4][TH][CW];
    __shared__ float col2[2][4][TH][C2W];
    __shared__ float wsum[4];

    const int bx   = blockIdx.x;
    const int b    = bx / (2 * NTH * NTW);
    int rem        = bx % (2 * NTH * NTW);
    const int half = rem / (NTH * NTW);
    rem            = rem % (NTH * NTW);
    const int h0   = (rem / NTW) * TH;
    const int w0   = (rem % NTW) * TW;
    const int t0   = half * OT_PER;

    const int tid = threadIdx.x;

    const float* pb = pred + (long long)b * T * H * W;
    const float* qb = targ + (long long)b * T * H * W;

    // ---- staging: 440 float4 items = 2 fields x 22 rows x 10 f4-cols ----
    const int item0 = tid;            // always active
    const int f0s = item0 / 220, rm0 = item0 % 220;
    const int r0s = rm0 / 10, c0s = rm0 % 10;
    const int gr0 = min(h0 + r0s, H - 1), gc0 = min(w0 + 4 * c0s, W - 4);
    const float* gb0 = (f0s ? qb : pb) + (long long)gr0 * W + gc0;
    const int o0 = r0s * SPW + 4 * c0s;

    const bool act1 = (tid < 184);
    const int item1 = 256 + tid;
    const int f1s = item1 / 220, rm1 = item1 % 220;
    const int r1s = rm1 / 10, c1s = rm1 % 10;
    const int gr1 = min(h0 + r1s, H - 1), gc1 = min(w0 + 4 * c1s, W - 4);
    const float* gb1 = (f1s ? qb : pb) + (long long)gr1 * W + gc1;
    const int o1 = r1s * SPW + 4 * c1s;

    float4 pr0, pr1;
    auto prefetchw = [&](int s) {
        const long long so = (long long)(t0 + s) * H * W;
        pr0 = *reinterpret_cast<const float4*>(gb0 + so);
        if (act1) pr1 = *reinterpret_cast<const float4*>(gb1 + so);
    };
    auto commitw = [&](int buf) {
        float* d0 = (f0s ? &sq[buf][0][0] : &sp[buf][0][0]) + o0;
        *reinterpret_cast<float4*>(d0) = pr0;
        if (act1) {
            float* d1 = (f1s ? &sq[buf][0][0] : &sp[buf][0][0]) + o1;
            *reinterpret_cast<float4*>(d1) = pr1;
        }
    };

    // ---- colsum mapping: 152 items = 8 row-pairs x 19 col-pairs ----
    const bool colw = (tid < 152);
    const int rp = tid / 19, cpi = tid % 19;
    const int cr0 = 2 * rp;          // output rows cr0, cr0+1
    const int cc  = 2 * cpi;         // cols cc, cc+1

    // ---- rowgather mapping: outputs (oh, 2k) and (oh, 2k+1) ----
    const int oh = tid >> 4, k = tid & 15;
    const bool vh = (h0 + oh < HO);
    const bool vE = vh && (w0 + 2 * k     < WO);
    const bool vO = vh && (w0 + 2 * k + 1 < WO);

    const float dr  = drange[b];
    const float C1v = (0.01f * dr) * (0.01f * dr);
    const float C2v = (0.03f * dr) * (0.03f * dr);
    const float inv  = 1.0f / (float)NPIX;
    const float covn = (float)NPIX / (float)(NPIX - 1);

    float rE[4][7], rO[4][7], tE[4], tO[4];
#pragma unroll
    for (int f = 0; f < 4; ++f) {
        tE[f] = tO[f] = 0.f;
#pragma unroll
        for (int j = 0; j < 7; ++j) { rE[f][j] = rO[f][j] = 0.f; }
    }
    float loss = 0.f;

    auto ssim1 = [&](const float* tt) {
        float ux  = tt[0] * inv, uy = tt[1] * inv;
        float u2  = tt[2] * inv, uxy = tt[3] * inv;
        float B2 = covn * (u2 - ux * ux - uy * uy) + C2v;
        float A2 = 2.f * covn * (uxy - ux * uy) + C2v;
        float A1 = 2.f * ux * uy + C1v;
        float B1 = ux * ux + uy * uy + C1v;
        return 1.f - (A1 * A2) / (B1 * B2);
    };

    // ---- prologue ----
    prefetchw(0);
    commitw(0);
    prefetchw(1);
    __syncthreads();

    for (int a = 0; a < 21; a += 7) {
#pragma unroll
        for (int jj = 0; jj < 7; ++jj) {
            const int s = a + jj;
            if (s < NS) {
                const int bs = s & 1, bn = bs ^ 1;

                if (s + 1 < NS) commitw(bn);

                if (colw) {
                    float2 mid[4], row0[4], row7[4];
#pragma unroll
                    for (int dy = 0; dy < 8; ++dy) {
                        float2 p = *reinterpret_cast<const float2*>(&sp[bs][cr0 + dy][cc]);
                        float2 q = *reinterpret_cast<const float2*>(&sq[bs][cr0 + dy][cc]);
                        float2 v[4];
                        v[0] = p;
                        v[1] = q;
                        v[2] = make_float2(fmaf(p.x, p.x, q.x * q.x),
                                           fmaf(p.y, p.y, q.y * q.y));
                        v[3] = make_float2(p.x * q.x, p.y * q.y);
                        if (dy == 0) {
#pragma unroll
                            for (int f = 0; f < 4; ++f) row0[f] = v[f];
                        } else if (dy == 7) {
#pragma unroll
                            for (int f = 0; f < 4; ++f) row7[f] = v[f];
                        } else if (dy == 1) {
#pragma unroll
                            for (int f = 0; f < 4; ++f) mid[f] = v[f];
                        } else {
#pragma unroll
                            for (int f = 0; f < 4; ++f) {
                                mid[f].x += v[f].x; mid[f].y += v[f].y;
                            }
                        }
                    }
#pragma unroll
                    for (int f = 0; f < 4; ++f) {
                        float ax = row0[f].x + mid[f].x;   // window @ row cr0, col cc
                        float ay = row0[f].y + mid[f].y;   // col cc+1
                        float bxv = mid[f].x + row7[f].x;  // window @ row cr0+1
                        float byv = mid[f].y + row7[f].y;
                        col[bs][f][cr0][cc]       = ax;
                        col[bs][f][cr0][cc + 1]   = ay;
                        col[bs][f][cr0 + 1][cc]     = bxv;
                        col[bs][f][cr0 + 1][cc + 1] = byv;
                        col2[bs][f][cr0][cpi]     = ax + ay;
                        col2[bs][f][cr0 + 1][cpi] = bxv + byv;
                    }
                }

                if (s + 2 < NS) prefetchw(s + 2);

                __syncthreads();   // col[bs] ready; sp[bn] committed

                // ---- rowgather: S8 via 4 pairs, then 2 outputs by subtracting singles
                float sEv[4], sOv[4];
#pragma unroll
                for (int f = 0; f < 4; ++f) {
                    const float* c2r = &col2[bs][f][oh][0];
                    float s8 = c2r[k] + c2r[k + 1] + c2r[k + 2] + c2r[k + 3];
                    const float* cr = &col[bs][f][oh][0];
                    sEv[f] = s8 - cr[2 * k + 7];
                    sOv[f] = s8 - cr[2 * k];
                }
#pragma unroll
                for (int f = 0; f < 4; ++f) {
                    tE[f] += sEv[f] - rE[f][jj];  rE[f][jj] = sEv[f];
                    tO[f] += sOv[f] - rO[f][jj];  rO[f][jj] = sOv[f];
                }

                if (s >= 6) {
                    if (vE) loss += ssim1(tE);
                    if (vO) loss += ssim1(tO);
                }
            }
        }
    }

    // ---- block reduction -> global atomic ----
    for (int off = 32; off > 0; off >>= 1)
        loss += __shfl_down(loss, off, 64);
    const int lane = tid & 63;
    const int wid  = tid >> 6;
    if (lane == 0) wsum[wid] = loss;
    __syncthreads();
    if (tid == 0) {
        float s = wsum[0] + wsum[1] + wsum[2] + wsum[3];
        atomicAdd(acc, (double)s);
    }
}

__global__ void ssim3d_finalize(const double* __restrict__ acc,
                                float* __restrict__ out)
{
    out[0] = (float)(acc[0] / (double)NOUT);
}

extern "C" void kernel_launch(void* const* d_in, const int* in_sizes, int n_in,
                              void* d_out, int out_size, void* d_ws, size_t ws_size,
                              hipStream_t stream)
{
    const float* pred   = (const float*)d_in[0];
    const float* targ   = (const float*)d_in[1];
    const float* drange = (const float*)d_in[2];
    float* out  = (float*)d_out;
    double* acc = (double*)d_ws;

    hipMemsetAsync(acc, 0, sizeof(double), stream);

    const int nblocks = B * 2 * NTH * NTW;  // 1600
    ssim3d_fused<<<nblocks, 256, 0, stream>>>(pred, targ, drange, acc);
    ssim3d_finalize<<<1, 1, 0, stream>>>(acc, out);
}